// Round 3
// baseline (197.160 us; speedup 1.0000x reference)
//
#include <hip/hip_runtime.h>

// ---------------------------------------------------------------------------
// VisualContrastiveLoss on MI355X
// loss = C + mean_i log(Z_i) - mean_i sim[i, lab_i],  C = 1/0.07
//   Z_i = sum_j exp(sim_ij - C)  (fixed shift: dots bounded by 1)
//   sim = (f f^T)/0.07, f = row-normalized visual_feat
// R14: SYMMETRY — compute only upper-triangular tiles.
// R16: tile-per-block, barrier-free — REGRESSED to 70us: Occupancy 18%
//   (64KB LDS -> 2 blk/CU), MfmaUtil 9.4%, all pipes idle = latency-bound;
//   scattered B-gathers (32 half-used lines/instr) + L2 thrash (FETCH 16.5MB).
// R17: OCCUPANCY + COALESCED GATHERS + L2 LOCALITY —
//   * 64x128 tiles: ldsA = 32KB -> 4 blk/CU = 16 waves/CU (50% occ, 2x TLP).
//     4160 equal blocks, pair-quadratic triangular decode. Crossing tiles
//     (j == i>>1) computed fully with ROW sums only; full tiles row+col
//     sums. Coverage: every sim element hits Z exactly once (verified
//     algebra: even/odd crossing tiles mirror each other's halves).
//   * fQ stored GRANULE-MAJOR (fQT[g][row], 16B granules, 32 planes of
//     128KB): B-frag loads = 16 rows x 16B contiguous per plane -> 16
//     fully-used 64B lines/instr (was 32 half-used). A-staging equally
//     coalesced. norm_kernel emits fQT via a 2KB LDS transpose.
//   * XCD-chunked bijective swizzle (4160 = 8*520): each XCD works a
//     contiguous tile range -> B footprint ~2-4MB fits its private L2.
// Kept: zero-conflict granule LDS layout for A (h(u)=2(u&3)+(u>>2)),
// FragU b128 frag loads, raw v_exp_f32, setprio around MFMA, one
// __syncthreads per block, exact-diagonal fixup in finalize.
// ---------------------------------------------------------------------------

typedef int i32x8 __attribute__((ext_vector_type(8)));
typedef float f32x4 __attribute__((ext_vector_type(4)));

#define B_N 8192
#define D_K 512
#define ROWB 512          // bytes per fp8 row
#define GRANP 131072      // bytes per granule plane: 8192 rows * 16B
#define NTILE2 4160       // 64x128 tiles in the pair-triangular cover
#define INVT 14.285714285714286f
// (1/0.07) * log2(e)
#define SCALE_LOG2 20.609929155556622f

#if defined(__has_builtin) && __has_builtin(__builtin_amdgcn_exp2f)
#define FAST_EXP2(x) __builtin_amdgcn_exp2f(x)
#else
#define FAST_EXP2(x) exp2f(x)
#endif

union FragU {
  int4 h[2];
  i32x8 v;
};

static __device__ __forceinline__ void load16_to_lds(const void* g, void* l) {
  __builtin_amdgcn_global_load_lds(
      (const __attribute__((address_space(1))) unsigned int*)g,
      (__attribute__((address_space(3))) unsigned int*)l, 16, 0, 0);
}

// ---- K1: 4 waves/block, one wave per row; normalize fp32 -> fp8 e4m3 --------
// Emits GRANULE-MAJOR fQT: byte (g*GRANP + row*16 + h*8) = granule g of row,
// half h. LDS transpose (2KB) keeps the global stores coalesced.
// Also zeroes Z (ws is poisoned before every launch).
__global__ __launch_bounds__(256)
void norm_kernel(const float* __restrict__ x,
                 unsigned char* __restrict__ fQT,
                 float* __restrict__ Z) {
  __shared__ unsigned char ldsN[4][512];
  const int t = threadIdx.x;
  const int wv = t >> 6;
  const int lane = t & 63;
  const int row0 = blockIdx.x * 4;
  const int row = row0 + wv;
  const float4* xr = (const float4*)(x + (size_t)row * D_K);
  float4 a = xr[2 * lane];
  float4 b = xr[2 * lane + 1];
  float s = a.x * a.x + a.y * a.y + a.z * a.z + a.w * a.w +
            b.x * b.x + b.y * b.y + b.z * b.z + b.w * b.w;
#pragma unroll
  for (int off = 1; off < 64; off <<= 1) s += __shfl_xor(s, off);
  const float inv = 1.0f / fmaxf(sqrtf(s), 1e-12f);
  int lo = 0, hi = 0;
  lo = __builtin_amdgcn_cvt_pk_fp8_f32(a.x * inv, a.y * inv, lo, false);
  lo = __builtin_amdgcn_cvt_pk_fp8_f32(a.z * inv, a.w * inv, lo, true);
  hi = __builtin_amdgcn_cvt_pk_fp8_f32(b.x * inv, b.y * inv, hi, false);
  hi = __builtin_amdgcn_cvt_pk_fp8_f32(b.z * inv, b.w * inv, hi, true);
  int2 p; p.x = lo; p.y = hi;
  ((int2*)&ldsN[wv][0])[lane] = p;  // row bytes [lane*8, +8)
  if (lane == 0) Z[row] = 0.0f;
  __syncthreads();
  // write out 4 rows x 512B = 2KB as 32 granule chunks of 64B (4 rows x 16B)
  const int g = t >> 3;        // granule 0..31
  const int sub = t & 7;       // 4 rows x 2 halves
  const int r = sub >> 1;
  const int h = sub & 1;
  const int2 v = *(const int2*)&ldsN[r][g * 16 + h * 8];
  *(int2*)(fQT + (size_t)g * GRANP + (size_t)(row0 + r) * 16 + h * 8) = v;
}

// ---- K2: upper-triangular fp8 similarity + softmax-denominator --------------
// One 64x128 tile per block; 4 waves, wave w owns cols w*32 (acc 4m x 2n).
// A (64 rows x full K) staged once into 4 zero-conflict granule planes
// (8KB each); B frags gathered straight from granule-major global (L2),
// pipelined 1 kk ahead in registers. One barrier; waves then free-run.
__global__ __launch_bounds__(256, 4)
void sim_kernel(const unsigned char* __restrict__ fQT,
                float* __restrict__ Z, float* __restrict__ T01,
                float* __restrict__ D) {
  __shared__ unsigned char ldsA[4][64 * 128];  // 32 KB

  // ---- XCD-chunked swizzle (4160 = 8 * 520, bijective) --------------------
  const int tt = ((blockIdx.x & 7) * 520) + (blockIdx.x >> 3);
  // ---- pair-quadratic triangular decode: tt -> (i, j) ---------------------
  // pair a holds rows i=2a,2a+1, each with cnt = 64-a tiles (j = a..63);
  // cumulative C(a) = a*(129-a).
  int a = (int)((129.0f - sqrtf(16641.0f - 4.0f * (float)tt)) * 0.5f);
  if (a < 0) a = 0;
  if (a > 63) a = 63;
  while (a < 63 && (a + 1) * (128 - a) <= tt) ++a;
  while (a > 0 && a * (129 - a) > tt) --a;
  const int rr_ = tt - a * (129 - a);
  const int cnt = 64 - a;
  const int hi_ = (rr_ >= cnt);
  const int i = 2 * a + hi_;
  const int j = a + (hi_ ? rr_ - cnt : rr_);
  const int i0 = i * 64, J0 = j * 128;
  const bool crossing = (j == (i >> 1));  // tile straddles the diagonal

  const int tid = threadIdx.x;
  const int lane = tid & 63;
  const int w = tid >> 6;  // wave -> col strip w*32

  // staging lane geometry: 8 rows x 8 slots(16B); slot s of row r holds
  // granule h(s^(r&7)), h(u)=2(u&3)+(u>>2) -> zero-conflict frag reads.
  const int srow = lane >> 3;
  const int sb = lane & 7;
  const int su = sb ^ srow;
  const int sgl = 2 * (su & 3) + (su >> 2);  // source granule within plane

  // fragment-read lane geometry
  const int fr = lane & 15;
  const int q = lane >> 4;
  const int swz = fr & 7;
  const int off0 = (q ^ swz) * 16;        // slot holding granule 2q
  const int off1 = ((q + 4) ^ swz) * 16;  // slot holding granule 2q+1

  // ---- stage A once: wave w stages rows w*16..+15, all 4 K-planes ----------
#pragma unroll
  for (int kk = 0; kk < 4; ++kk) {
#pragma unroll
    for (int rb = 0; rb < 16; rb += 8) {
      const unsigned char* gA = fQT + (size_t)(kk * 8 + sgl) * GRANP +
                                (size_t)(i0 + w * 16 + rb + srow) * 16;
      load16_to_lds(gA, ldsA[kk] + (w * 16 + rb) * 128);
    }
  }

  // B frag source: granule planes (kk*8+2q, kk*8+2q+1), row J0+w*32+n*16+fr.
  const size_t bRow = (size_t)(J0 + w * 32 + fr) * 16;

  f32x4 acc[4][2];
#pragma unroll
  for (int m = 0; m < 4; ++m)
#pragma unroll
    for (int n = 0; n < 2; ++n) acc[m][n] = (f32x4){0.f, 0.f, 0.f, 0.f};

  FragU b0[2], b1[2];
#pragma unroll
  for (int n = 0; n < 2; ++n) {  // preload kk=0 B frags
    b0[n].h[0] = *(const int4*)(fQT + (size_t)(2 * q) * GRANP + bRow + n * 256);
    b0[n].h[1] =
        *(const int4*)(fQT + (size_t)(2 * q + 1) * GRANP + bRow + n * 256);
  }

  __syncthreads();  // A staged (the only barrier in the kernel)

#pragma unroll
  for (int kk = 0; kk < 4; ++kk) {
    FragU* bc = (kk & 1) ? b1 : b0;  // static after unroll (rule 20)
    FragU* bn = (kk & 1) ? b0 : b1;
    if (kk < 3) {  // prefetch next kk's B frags
      const size_t p0 = (size_t)((kk + 1) * 8 + 2 * q) * GRANP + bRow;
#pragma unroll
      for (int n = 0; n < 2; ++n) {
        bn[n].h[0] = *(const int4*)(fQT + p0 + n * 256);
        bn[n].h[1] = *(const int4*)(fQT + p0 + GRANP + n * 256);
      }
    }
    __builtin_amdgcn_s_setprio(1);
#pragma unroll
    for (int mh = 0; mh < 2; ++mh) {  // m-split: av[2] live, not av[4]
      i32x8 av[2];
#pragma unroll
      for (int m = 0; m < 2; ++m) {
        const unsigned char* ra = ldsA[kk] + ((mh * 2 + m) * 16 + fr) * 128;
        FragU u;
        u.h[0] = *(const int4*)(ra + off0);
        u.h[1] = *(const int4*)(ra + off1);
        av[m] = u.v;
      }
#pragma unroll
      for (int m = 0; m < 2; ++m)
#pragma unroll
        for (int n = 0; n < 2; ++n)
          acc[mh * 2 + m][n] = __builtin_amdgcn_mfma_scale_f32_16x16x128_f8f6f4(
              av[m], bc[n].v, acc[mh * 2 + m][n], 0, 0, 0, 127, 0, 127);
    }
    __builtin_amdgcn_s_setprio(0);
  }

  // ---- epilogue (barrier-free; registers + global only) --------------------
  // T01: sim[0,c], sim[1,c] from rows 0,1 (i==0 tiles; q==0 -> r=0,1)
  if (i == 0 && q == 0) {
#pragma unroll
    for (int n = 0; n < 2; ++n) {
      const int col = J0 + w * 32 + n * 16 + fr;
      T01[col * 2 + 0] = acc[0][n][0] * INVT;
      T01[col * 2 + 1] = acc[0][n][1] * INVT;
    }
  }

  // D: diagonal dots (crossing tiles contain every row's diagonal exactly once)
  if (crossing) {
#pragma unroll
    for (int m = 0; m < 4; ++m)
#pragma unroll
      for (int n = 0; n < 2; ++n) {
        const int col = J0 + w * 32 + n * 16 + fr;
#pragma unroll
        for (int r = 0; r < 4; ++r) {
          const int row = i0 + m * 16 + q * 4 + r;
          if (row == col) D[row] = acc[m][n][r];
        }
      }
  }

  // Z: row partials always. Col sums only for non-crossing (fully-upper)
  // tiles — crossing tiles' mirror coverage comes from their partner
  // crossing tile's row sums (even/odd i pair).
  float Zp[4][4];
#pragma unroll
  for (int m = 0; m < 4; ++m)
#pragma unroll
    for (int r = 0; r < 4; ++r) Zp[m][r] = 0.0f;

#pragma unroll
  for (int n = 0; n < 2; ++n) {
    float cs = 0.0f;
#pragma unroll
    for (int m = 0; m < 4; ++m)
#pragma unroll
      for (int r = 0; r < 4; ++r) {
        const float e = FAST_EXP2((acc[m][n][r] - 1.0f) * SCALE_LOG2);
        Zp[m][r] += e;
        cs += e;
      }
    if (!crossing) {
      cs += __shfl_xor(cs, 16);
      cs += __shfl_xor(cs, 32);
      if (q == 0) atomicAdd(&Z[J0 + w * 32 + n * 16 + fr], cs);
    }
  }

  // row sums: reduce Zp across the 16 col-lanes, then atomicAdd
#pragma unroll
  for (int m = 0; m < 4; ++m)
#pragma unroll
    for (int r = 0; r < 4; ++r) {
      float v = Zp[m][r];
      v += __shfl_xor(v, 1);
      v += __shfl_xor(v, 2);
      v += __shfl_xor(v, 4);
      v += __shfl_xor(v, 8);
      if (fr == 0) atomicAdd(&Z[i0 + m * 16 + q * 4 + r], v);
    }
}

// ---- K3: labels + exact-diagonal fixup + final loss reduction ---------------
// 1024 threads, 8 rows each, all loads batched/independent.
__global__ __launch_bounds__(1024)
void finalize_kernel(const float* __restrict__ Z,
                     const float* __restrict__ T01,
                     const float* __restrict__ D,
                     const int* __restrict__ ids,
                     const int* __restrict__ anchor,
                     float* __restrict__ out) {
  __shared__ float red[1024];
  const int t = threadIdx.x;
  const int anchor_id = ids[anchor[0]];
  const int sameLast = (ids[B_N - 1] == anchor_id);
  const int samePrev = (ids[B_N - 2] == anchor_id);
  int i[8], id[8];
  float z[8], d[8], t0[8], t1[8];
#pragma unroll
  for (int u = 0; u < 8; ++u) {
    i[u] = u * 1024 + t;
    z[u] = Z[i[u]];
    d[u] = D[i[u]];
    t0[u] = T01[i[u] * 2 + 0];
    t1[u] = T01[i[u] * 2 + 1];
    id[u] = ids[i[u]];
  }
  float sum = 0.0f;
#pragma unroll
  for (int u = 0; u < 8; ++u) {
    const int same_i = (id[u] == anchor_id);
    const int lab =
        (i[u] < B_N - 1) ? (same_i & sameLast) : (sameLast & samePrev);
    const float tt = lab ? t1[u] : t0[u];
    // replace quantized diag contribution with the exact value exp(0)=1
    const float Zc = z[u] - FAST_EXP2((d[u] - 1.0f) * SCALE_LOG2) + 1.0f;
    sum += tt - (INVT + logf(Zc));
  }
  red[t] = sum;
  __syncthreads();
  for (int off = 512; off > 0; off >>= 1) {
    if (t < off) red[t] += red[t + off];
    __syncthreads();
  }
  if (t == 0) out[0] = -red[0] / (float)B_N;
}

// ---------------------------------------------------------------------------
extern "C" void kernel_launch(void* const* d_in, const int* in_sizes, int n_in,
                              void* d_out, int out_size, void* d_ws, size_t ws_size,
                              hipStream_t stream) {
  const float* x = (const float*)d_in[0];
  const int* ids = (const int*)d_in[1];
  const int* anchor = (const int*)d_in[2];
  float* out = (float*)d_out;

  unsigned char* fQT = (unsigned char*)d_ws;                   // 4 MB fp8 (granule-major)
  float* Z = (float*)((char*)d_ws + (size_t)B_N * ROWB);       // 32 KB
  float* T01 = Z + B_N;                                        // 64 KB
  float* D = T01 + 2 * B_N;                                    // 32 KB

  norm_kernel<<<B_N / 4, 256, 0, stream>>>(x, fQT, Z);
  sim_kernel<<<NTILE2, 256, 0, stream>>>(fQT, Z, T01, D);
  finalize_kernel<<<1, 1024, 0, stream>>>(Z, T01, D, ids, anchor, out);
}

// Round 4
// 187.722 us; speedup vs baseline: 1.0503x; 1.0503x over previous
//
#include <hip/hip_runtime.h>

// ---------------------------------------------------------------------------
// VisualContrastiveLoss on MI355X
// loss = C + mean_i log(Z_i) - mean_i sim[i, lab_i],  C = 1/0.07
//   Z_i = sum_j exp(sim_ij - C)  (fixed shift: dots bounded by 1)
//   sim = (f f^T)/0.07, f = row-normalized visual_feat
// R14: SYMMETRY — sim_ij = sim_ji, compute only tiles J >= I (2080/4096).
// R16/R17: tile-per-block + global B-gather REGRESSED (70/130us): B must be
//   LDS-broadcast; multi-tile blocks amortize A; balance via grid pairing.
//   -> REVERTED to the R15 skeleton (best: 104us total, sim ~46us).
// R18: A-FRAGS IN REGISTERS — pipe arithmetic says LDS frag reads (64
//   ds_read_b128/tile-kk, ~25k cyc/CU) outweigh MFMA (~18k cyc/CU); half
//   are A-frags re-read every J tile though the row band is fixed. At 2
//   blocks/CU (LDS-capped) VGPR<=256 is free: hold A kk=1,2,3 in regs
//   (96 VGPR, loaded once via the R15-validated direct gather); kk=0 stays
//   in LDS (peak VGPR ~230, no spill). ldsA 64->16KB, ldsB dbuf 32KB.
//   Keep R15's counted-vmcnt 1-deep B pipeline (harness-passed), grid
//   (32,16) pairing, zero-conflict granule layouts, epilogue unchanged.
// ---------------------------------------------------------------------------

typedef int i32x8 __attribute__((ext_vector_type(8)));
typedef float f32x4 __attribute__((ext_vector_type(4)));

#define B_N 8192
#define D_K 512
#define ROWB 512  // bytes per fp8 row
#define INVT 14.285714285714286f
// (1/0.07) * log2(e)
#define SCALE_LOG2 20.609929155556622f

#if defined(__has_builtin) && __has_builtin(__builtin_amdgcn_exp2f)
#define FAST_EXP2(x) __builtin_amdgcn_exp2f(x)
#else
#define FAST_EXP2(x) exp2f(x)
#endif

union FragU {
  int4 h[2];
  i32x8 v;
};

static __device__ __forceinline__ void load16_to_lds(const void* g, void* l) {
  __builtin_amdgcn_global_load_lds(
      (const __attribute__((address_space(1))) unsigned int*)g,
      (__attribute__((address_space(3))) unsigned int*)l, 16, 0, 0);
}

// Raw workgroup barrier WITHOUT the vmcnt(0) drain __syncthreads emits.
// Fenced on both sides (IR memory clobber + machine sched_barrier, rule 18).
static __device__ __forceinline__ void bar_nodrain() {
  __builtin_amdgcn_sched_barrier(0);
  asm volatile("" ::: "memory");
  __builtin_amdgcn_s_barrier();
  asm volatile("" ::: "memory");
  __builtin_amdgcn_sched_barrier(0);
}

#define VM_WAIT(N) asm volatile("s_waitcnt vmcnt(" #N ")" ::: "memory")

// ---- K1: 4 waves/block, one wave per row; normalize fp32 -> fp8 e4m3 --------
// Also zeroes Z (ws is poisoned before every launch).
__global__ __launch_bounds__(256)
void norm_kernel(const float* __restrict__ x,
                 unsigned char* __restrict__ fQ,
                 float* __restrict__ Z) {
  const int row = blockIdx.x * 4 + (threadIdx.x >> 6);
  const int lane = threadIdx.x & 63;
  const float4* xr = (const float4*)(x + (size_t)row * D_K);
  float4 a = xr[2 * lane];
  float4 b = xr[2 * lane + 1];
  float s = a.x * a.x + a.y * a.y + a.z * a.z + a.w * a.w +
            b.x * b.x + b.y * b.y + b.z * b.z + b.w * b.w;
#pragma unroll
  for (int off = 1; off < 64; off <<= 1) s += __shfl_xor(s, off);
  const float inv = 1.0f / fmaxf(sqrtf(s), 1e-12f);
  int lo = 0, hi = 0;
  lo = __builtin_amdgcn_cvt_pk_fp8_f32(a.x * inv, a.y * inv, lo, false);
  lo = __builtin_amdgcn_cvt_pk_fp8_f32(a.z * inv, a.w * inv, lo, true);
  hi = __builtin_amdgcn_cvt_pk_fp8_f32(b.x * inv, b.y * inv, hi, false);
  hi = __builtin_amdgcn_cvt_pk_fp8_f32(b.z * inv, b.w * inv, hi, true);
  int2 p; p.x = lo; p.y = hi;
  ((int2*)(fQ + (size_t)row * ROWB))[lane] = p;
  if (lane == 0) Z[row] = 0.0f;
}

// ---- K2: upper-triangular fp8 similarity + softmax-denominator --------------
// grid (32, 16): by<8 -> row band I=bx; by>=8 -> I=63-bx. Tile cols
// J in {J >= I, J == (by&7) mod 8}. 4 waves 2x2; wave owns 64x64 C via 4x4
// frags of 16x16x128 MX-fp8 MFMA (scale=1). A: kk=0 plane staged to LDS
// (zero-conflict granule layout: slot s of row r holds granule h(s^(r&7)),
// h(u)=2(u&3)+(u>>2)); kk=1,2,3 held in registers (direct frag gather,
// natural granule order). B staged per kk, double-buffered, counted vmcnt.
__global__ __launch_bounds__(256, 2)
void sim_kernel(const unsigned char* __restrict__ fQ,
                float* __restrict__ Z, float* __restrict__ T01,
                float* __restrict__ D) {
  __shared__ unsigned char ldsA0[128 * 128];     // 16 KB: A plane kk=0
  __shared__ unsigned char ldsB[2 * 128 * 128];  // 32 KB: double-buffered B

  const int tid = threadIdx.x;
  const int lane = tid & 63;
  const int w = tid >> 6;
  const int wm = w & 1;       // wave row strip (0/1) -> rows wm*64..
  const int wn = w >> 1;      // wave col strip (0/1) -> cols wn*64..
  const int bx = blockIdx.x, by = blockIdx.y;
  const int b = by & 7;
  const int I = (by < 8) ? bx : (63 - bx);    // row band index
  const int Jfirst = I + ((b - I) & 7);       // first J >= I with J==b (mod 8)
  if (Jfirst > 63) return;                    // no tiles for this block
  const int I0 = I * 128;

  // staging lane geometry: 8 rows x 8 slots(16B) per instruction.
  const int srow = lane >> 3;                 // 0..7
  const int sb = lane & 7;                    // dest slot
  const int su = sb ^ srow;
  const int sg = 2 * (su & 3) + (su >> 2);    // source granule
  const size_t sOff = (size_t)srow * ROWB + sg * 16;  // bytes

  // fragment-read lane geometry
  const int fr = lane & 15;   // M/N index within 16
  const int q = lane >> 4;    // quad -> k chunk of 32B
  const int swz = fr & 7;     // row&7 of the frag row

  const int raRow = (wm * 64 + fr) * 128;
  const int rbRow = (wn * 64 + fr) * 128;
  const int off0 = (q ^ swz) * 16;        // slot holding granule 2q
  const int off1 = ((q + 4) ^ swz) * 16;  // slot holding granule 2q+1

  // ---- A chunks kk=1,2,3 -> registers (frag-layout-identical gather) -------
  // Frag for (kk, m): row (I0 + wm*64 + m*16 + fr), bytes kk*128 + q*32.
  FragU uA[3][4];  // [kk-1][m], 96 VGPR
  {
    const unsigned char* aBase =
        fQ + (size_t)(I0 + wm * 64 + fr) * ROWB + q * 32;
#pragma unroll
    for (int k = 0; k < 3; ++k) {
#pragma unroll
      for (int m = 0; m < 4; ++m) {
        const unsigned char* p = aBase + (size_t)(m * 16) * ROWB + (k + 1) * 128;
        uA[k][m].h[0] = *(const int4*)(p);
        uA[k][m].h[1] = *(const int4*)(p + 16);
      }
    }
  }
  // Force the vmcnt wait for uA HERE (once, pre-pipeline) so no conservative
  // vmcnt wait lands inside the K loop.
#pragma unroll
  for (int k = 0; k < 3; ++k)
#pragma unroll
    for (int m = 0; m < 4; ++m) asm volatile("" ::"v"(uA[k][m].v));

  // ---- stage A plane kk=0: wave w stages rows w*32..+31 (4 instrs) ---------
  {
    const unsigned char* gA = fQ + (size_t)(I0 + w * 32) * ROWB + sOff;
    unsigned char* lA = ldsA0 + (w * 32) * 128;
#pragma unroll
    for (int rr = 0; rr < 32; rr += 8)
      load16_to_lds(gA + (size_t)rr * ROWB, lA + rr * 128);
  }

  // ---- prologue: stage B(Jfirst, chunk 0) into buffer 0 --------------------
  int curOff = 0;  // active B buffer byte offset (0 / 16384)
  {
    const unsigned char* gB =
        fQ + (size_t)(Jfirst * 128 + w * 32) * ROWB + sOff;
    unsigned char* lB = ldsB + (w * 32) * 128;
#pragma unroll
    for (int rr = 0; rr < 32; rr += 8)
      load16_to_lds(gB + (size_t)rr * ROWB, lB + rr * 128);
  }

  float Zp[4][4];
#pragma unroll
  for (int m = 0; m < 4; ++m)
#pragma unroll
    for (int r = 0; r < 4; ++r) Zp[m][r] = 0.0f;

  f32x4 acc[4][4];

#pragma unroll 1
  for (int J = Jfirst; J < 64; J += 8) {
    const int J0 = J * 128;
#pragma unroll
    for (int m = 0; m < 4; ++m)
#pragma unroll
      for (int n = 0; n < 4; ++n) acc[m][n] = (f32x4){0.f, 0.f, 0.f, 0.f};

    // ---- kk = 0: A from ldsA0; stage B chunk 1 ----------------------------
    {
      {  // issue B(J,1) into the other buffer
        const unsigned char* gB =
            fQ + (size_t)(J0 + w * 32) * ROWB + 1 * 128 + sOff;
        unsigned char* lB = ldsB + (curOff ^ 16384) + (w * 32) * 128;
#pragma unroll
        for (int rr = 0; rr < 32; rr += 8)
          load16_to_lds(gB + (size_t)rr * ROWB, lB + rr * 128);
      }
      VM_WAIT(4);  // A0 + B(J,0) retired; B(J,1) stays in flight
      bar_nodrain();

      const unsigned char* rbBase = ldsB + curOff + rbRow;
      i32x8 av[4];
#pragma unroll
      for (int m = 0; m < 4; ++m) {
        const unsigned char* ra = ldsA0 + raRow + m * 16 * 128;
        FragU u;
        u.h[0] = *(const int4*)(ra + off0);
        u.h[1] = *(const int4*)(ra + off1);
        av[m] = u.v;
      }
      __builtin_amdgcn_s_setprio(1);
#pragma unroll
      for (int n = 0; n < 4; ++n) {
        const unsigned char* rb = rbBase + n * 16 * 128;
        FragU ub;
        ub.h[0] = *(const int4*)(rb + off0);
        ub.h[1] = *(const int4*)(rb + off1);
#pragma unroll
        for (int m = 0; m < 4; ++m)
          acc[m][n] = __builtin_amdgcn_mfma_scale_f32_16x16x128_f8f6f4(
              av[m], ub.v, acc[m][n], 0, 0, 0, 127, 0, 127);
      }
      __builtin_amdgcn_s_setprio(0);
      bar_nodrain();  // all waves done reading buf[cur] before its reuse
      curOff ^= 16384;
    }

    // ---- kk = 1,2: A from registers; stage B chunk kk+1 --------------------
#pragma unroll
    for (int k = 0; k < 2; ++k) {
      {  // issue B(J,k+2)
        const unsigned char* gB =
            fQ + (size_t)(J0 + w * 32) * ROWB + (k + 2) * 128 + sOff;
        unsigned char* lB = ldsB + (curOff ^ 16384) + (w * 32) * 128;
#pragma unroll
        for (int rr = 0; rr < 32; rr += 8)
          load16_to_lds(gB + (size_t)rr * ROWB, lB + rr * 128);
      }
      VM_WAIT(4);  // own previous stage retired; the 4 just issued in flight
      bar_nodrain();

      const unsigned char* rbBase = ldsB + curOff + rbRow;
      __builtin_amdgcn_s_setprio(1);
#pragma unroll
      for (int n = 0; n < 4; ++n) {
        const unsigned char* rb = rbBase + n * 16 * 128;
        FragU ub;
        ub.h[0] = *(const int4*)(rb + off0);
        ub.h[1] = *(const int4*)(rb + off1);
#pragma unroll
        for (int m = 0; m < 4; ++m)
          acc[m][n] = __builtin_amdgcn_mfma_scale_f32_16x16x128_f8f6f4(
              uA[k][m].v, ub.v, acc[m][n], 0, 0, 0, 127, 0, 127);
      }
      __builtin_amdgcn_s_setprio(0);
      bar_nodrain();
      curOff ^= 16384;
    }

    // ---- kk = 3: A from registers; prefetch next J's chunk 0 ---------------
    const bool hasNext = (J + 8) < 64;
    if (hasNext) {
      const unsigned char* gB =
          fQ + (size_t)((J + 8) * 128 + w * 32) * ROWB + sOff;
      unsigned char* lB = ldsB + (curOff ^ 16384) + (w * 32) * 128;
#pragma unroll
      for (int rr = 0; rr < 32; rr += 8)
        load16_to_lds(gB + (size_t)rr * ROWB, lB + rr * 128);
      VM_WAIT(4);
    } else {
      VM_WAIT(0);  // nothing issued beyond our own last stage: full drain
    }
    bar_nodrain();
    {
      const unsigned char* rbBase = ldsB + curOff + rbRow;
      __builtin_amdgcn_s_setprio(1);
#pragma unroll
      for (int n = 0; n < 4; ++n) {
        const unsigned char* rb = rbBase + n * 16 * 128;
        FragU ub;
        ub.h[0] = *(const int4*)(rb + off0);
        ub.h[1] = *(const int4*)(rb + off1);
#pragma unroll
        for (int m = 0; m < 4; ++m)
          acc[m][n] = __builtin_amdgcn_mfma_scale_f32_16x16x128_f8f6f4(
              uA[2][m].v, ub.v, acc[m][n], 0, 0, 0, 127, 0, 127);
      }
      __builtin_amdgcn_s_setprio(0);
    }
    curOff ^= 16384;
    // Buffer-reuse barrier deferred to loop bottom — epilogue is
    // register/global-only, so waves drift while the prefetched next-J
    // chunk 0 is in flight.

    // T01: sim[0,c], sim[1,c] from rows 0,1 (band I==0 only)
    if (I == 0 && wm == 0) {
      if (q == 0) {
#pragma unroll
        for (int n = 0; n < 4; ++n) {
          const int col = J0 + wn * 64 + n * 16 + fr;
          T01[col * 2 + 0] = acc[0][n][0] * INVT;
          T01[col * 2 + 1] = acc[0][n][1] * INVT;
        }
      }
    }

    // D: diagonal dots, from the diagonal tile only
    if (J == I) {
#pragma unroll
      for (int m = 0; m < 4; ++m)
#pragma unroll
        for (int n = 0; n < 4; ++n) {
          const int col = J0 + wn * 64 + n * 16 + fr;
#pragma unroll
          for (int r = 0; r < 4; ++r) {
            const int row = I0 + wm * 64 + m * 16 + q * 4 + r;
            if (row == col) D[row] = acc[m][n][r];
          }
        }
    }

    // Z: row partials always; column sums for off-diag tiles (transpose
    // contribution to Z[J-band]).
    const bool offd = (J != I);
#pragma unroll
    for (int n = 0; n < 4; ++n) {
      float cs = 0.0f;
#pragma unroll
      for (int m = 0; m < 4; ++m)
#pragma unroll
        for (int r = 0; r < 4; ++r) {
          const float e = FAST_EXP2((acc[m][n][r] - 1.0f) * SCALE_LOG2);
          Zp[m][r] += e;
          cs += e;
        }
      if (offd) {
        cs += __shfl_xor(cs, 16);
        cs += __shfl_xor(cs, 32);
        if (q == 0) atomicAdd(&Z[J0 + wn * 64 + n * 16 + fr], cs);
      }
    }

    bar_nodrain();  // buf[cur] (just read at kk=3) may be restaged next iter
  }

  // row sums: reduce Zp across the 16 col-lanes, then atomicAdd
#pragma unroll
  for (int m = 0; m < 4; ++m)
#pragma unroll
    for (int r = 0; r < 4; ++r) {
      float v = Zp[m][r];
      v += __shfl_xor(v, 1);
      v += __shfl_xor(v, 2);
      v += __shfl_xor(v, 4);
      v += __shfl_xor(v, 8);
      if (fr == 0) atomicAdd(&Z[I0 + wm * 64 + m * 16 + q * 4 + r], v);
    }
}

// ---- K3: labels + exact-diagonal fixup + final loss reduction ---------------
// 1024 threads, 8 rows each, all loads batched/independent.
__global__ __launch_bounds__(1024)
void finalize_kernel(const float* __restrict__ Z,
                     const float* __restrict__ T01,
                     const float* __restrict__ D,
                     const int* __restrict__ ids,
                     const int* __restrict__ anchor,
                     float* __restrict__ out) {
  __shared__ float red[1024];
  const int t = threadIdx.x;
  const int anchor_id = ids[anchor[0]];
  const int sameLast = (ids[B_N - 1] == anchor_id);
  const int samePrev = (ids[B_N - 2] == anchor_id);
  int i[8], id[8];
  float z[8], d[8], t0[8], t1[8];
#pragma unroll
  for (int u = 0; u < 8; ++u) {
    i[u] = u * 1024 + t;
    z[u] = Z[i[u]];
    d[u] = D[i[u]];
    t0[u] = T01[i[u] * 2 + 0];
    t1[u] = T01[i[u] * 2 + 1];
    id[u] = ids[i[u]];
  }
  float sum = 0.0f;
#pragma unroll
  for (int u = 0; u < 8; ++u) {
    const int same_i = (id[u] == anchor_id);
    const int lab =
        (i[u] < B_N - 1) ? (same_i & sameLast) : (sameLast & samePrev);
    const float tt = lab ? t1[u] : t0[u];
    // replace quantized diag contribution with the exact value exp(0)=1
    const float Zc = z[u] - FAST_EXP2((d[u] - 1.0f) * SCALE_LOG2) + 1.0f;
    sum += tt - (INVT + logf(Zc));
  }
  red[t] = sum;
  __syncthreads();
  for (int off = 512; off > 0; off >>= 1) {
    if (t < off) red[t] += red[t + off];
    __syncthreads();
  }
  if (t == 0) out[0] = -red[0] / (float)B_N;
}

// ---------------------------------------------------------------------------
extern "C" void kernel_launch(void* const* d_in, const int* in_sizes, int n_in,
                              void* d_out, int out_size, void* d_ws, size_t ws_size,
                              hipStream_t stream) {
  const float* x = (const float*)d_in[0];
  const int* ids = (const int*)d_in[1];
  const int* anchor = (const int*)d_in[2];
  float* out = (float*)d_out;

  unsigned char* fQ = (unsigned char*)d_ws;                    // 4 MB fp8
  float* Z = (float*)((char*)d_ws + (size_t)B_N * ROWB);       // 32 KB
  float* T01 = Z + B_N;                                        // 64 KB
  float* D = T01 + 2 * B_N;                                    // 32 KB

  norm_kernel<<<B_N / 4, 256, 0, stream>>>(x, fQ, Z);
  sim_kernel<<<dim3(32, 16), 256, 0, stream>>>(fQ, Z, T01, D);
  finalize_kernel<<<1, 1024, 0, stream>>>(Z, T01, D, ids, anchor, out);
}

// Round 5
// 185.165 us; speedup vs baseline: 1.0648x; 1.0138x over previous
//
#include <hip/hip_runtime.h>

// ---------------------------------------------------------------------------
// VisualContrastiveLoss on MI355X
// loss = C + mean_i log(Z_i) - mean_i sim[i, lab_i],  C = 1/0.07
//   Z_i = sum_j exp(sim_ij - C)  (fixed shift: dots bounded by 1)
//   sim = (f f^T)/0.07, f = row-normalized visual_feat
// R14: SYMMETRY — sim_ij = sim_ji, compute only tiles J >= I (2080/4096).
// R16/R17: tile-per-block + global B-gather REGRESSED: B must be
//   LDS-broadcast; multi-tile blocks amortize A; balance via grid pairing.
// R18: A-frags (kk=1,2,3) in registers — REGRESSED to 120us, but counters
//   show WHY: compiler heuristic pinned VGPR=128 and SPILLED uA to scratch
//   (FETCH 202MB, WRITE 145MB of spill traffic). The idea was never tested.
// R19: FORCE THE REGISTER BUDGET — amdgpu_waves_per_eu(2,2): occupancy is
//   LDS/wave-capped at 2 waves/EU anyway (8 waves/CU), so 256 VGPR/wave is
//   free; min=max=2 tells the allocator so. uA (96 VGPR) now lives in
//   registers: A-frag LDS reads for kk=1,2,3 vanish (LDS pipe ~1536->~960
//   cyc/phase-pair), A lgkm chains leave the critical path, LDS 48KB.
//   + finalize split: 8 blocks + device-scope ticket finish (was 1 block,
//   8us of serial logf on one CU).
//   Expected counters: VGPR ~200-240, FETCH ~17MB, WRITE ~10MB; spill
//   signature (huge FETCH/WRITE) = attribute didn't take -> shelve A-in-reg.
// ---------------------------------------------------------------------------

typedef int i32x8 __attribute__((ext_vector_type(8)));
typedef float f32x4 __attribute__((ext_vector_type(4)));

#define B_N 8192
#define D_K 512
#define ROWB 512  // bytes per fp8 row
#define INVT 14.285714285714286f
// (1/0.07) * log2(e)
#define SCALE_LOG2 20.609929155556622f

#if defined(__has_builtin) && __has_builtin(__builtin_amdgcn_exp2f)
#define FAST_EXP2(x) __builtin_amdgcn_exp2f(x)
#else
#define FAST_EXP2(x) exp2f(x)
#endif

union FragU {
  int4 h[2];
  i32x8 v;
};

static __device__ __forceinline__ void load16_to_lds(const void* g, void* l) {
  __builtin_amdgcn_global_load_lds(
      (const __attribute__((address_space(1))) unsigned int*)g,
      (__attribute__((address_space(3))) unsigned int*)l, 16, 0, 0);
}

// Raw workgroup barrier WITHOUT the vmcnt(0) drain __syncthreads emits.
// Fenced on both sides (IR memory clobber + machine sched_barrier, rule 18).
static __device__ __forceinline__ void bar_nodrain() {
  __builtin_amdgcn_sched_barrier(0);
  asm volatile("" ::: "memory");
  __builtin_amdgcn_s_barrier();
  asm volatile("" ::: "memory");
  __builtin_amdgcn_sched_barrier(0);
}

#define VM_WAIT(N) asm volatile("s_waitcnt vmcnt(" #N ")" ::: "memory")

// ---- K1: 4 waves/block, one wave per row; normalize fp32 -> fp8 e4m3 --------
// Also zeroes Z, S, ticket (ws is poisoned before every launch).
__global__ __launch_bounds__(256)
void norm_kernel(const float* __restrict__ x,
                 unsigned char* __restrict__ fQ,
                 float* __restrict__ Z,
                 float* __restrict__ S,
                 int* __restrict__ ticket) {
  const int row = blockIdx.x * 4 + (threadIdx.x >> 6);
  const int lane = threadIdx.x & 63;
  const float4* xr = (const float4*)(x + (size_t)row * D_K);
  float4 a = xr[2 * lane];
  float4 b = xr[2 * lane + 1];
  float s = a.x * a.x + a.y * a.y + a.z * a.z + a.w * a.w +
            b.x * b.x + b.y * b.y + b.z * b.z + b.w * b.w;
#pragma unroll
  for (int off = 1; off < 64; off <<= 1) s += __shfl_xor(s, off);
  const float inv = 1.0f / fmaxf(sqrtf(s), 1e-12f);
  int lo = 0, hi = 0;
  lo = __builtin_amdgcn_cvt_pk_fp8_f32(a.x * inv, a.y * inv, lo, false);
  lo = __builtin_amdgcn_cvt_pk_fp8_f32(a.z * inv, a.w * inv, lo, true);
  hi = __builtin_amdgcn_cvt_pk_fp8_f32(b.x * inv, b.y * inv, hi, false);
  hi = __builtin_amdgcn_cvt_pk_fp8_f32(b.z * inv, b.w * inv, hi, true);
  int2 p; p.x = lo; p.y = hi;
  ((int2*)(fQ + (size_t)row * ROWB))[lane] = p;
  if (lane == 0) Z[row] = 0.0f;
  if (blockIdx.x == 0 && threadIdx.x == 0) {
    S[0] = 0.0f;
    ticket[0] = 0;
  }
}

// ---- K2: upper-triangular fp8 similarity + softmax-denominator --------------
// grid (32, 16): by<8 -> row band I=bx; by>=8 -> I=63-bx. Tile cols
// J in {J >= I, J == (by&7) mod 8}. 4 waves 2x2; wave owns 64x64 C via 4x4
// frags of 16x16x128 MX-fp8 MFMA (scale=1). A: kk=0 plane staged to LDS
// (zero-conflict granule layout: slot s of row r holds granule h(s^(r&7)),
// h(u)=2(u&3)+(u>>2)); kk=1,2,3 held in registers (direct frag gather,
// natural granule order). B staged per kk, double-buffered, counted vmcnt.
__global__ __attribute__((amdgpu_flat_work_group_size(256, 256)))
__attribute__((amdgpu_waves_per_eu(2, 2)))
void sim_kernel(const unsigned char* __restrict__ fQ,
                float* __restrict__ Z, float* __restrict__ T01,
                float* __restrict__ D) {
  __shared__ unsigned char ldsA0[128 * 128];     // 16 KB: A plane kk=0
  __shared__ unsigned char ldsB[2 * 128 * 128];  // 32 KB: double-buffered B

  const int tid = threadIdx.x;
  const int lane = tid & 63;
  const int w = tid >> 6;
  const int wm = w & 1;       // wave row strip (0/1) -> rows wm*64..
  const int wn = w >> 1;      // wave col strip (0/1) -> cols wn*64..
  const int bx = blockIdx.x, by = blockIdx.y;
  const int b = by & 7;
  const int I = (by < 8) ? bx : (63 - bx);    // row band index
  const int Jfirst = I + ((b - I) & 7);       // first J >= I with J==b (mod 8)
  if (Jfirst > 63) return;                    // no tiles for this block
  const int I0 = I * 128;

  // staging lane geometry: 8 rows x 8 slots(16B) per instruction.
  const int srow = lane >> 3;                 // 0..7
  const int sb = lane & 7;                    // dest slot
  const int su = sb ^ srow;
  const int sg = 2 * (su & 3) + (su >> 2);    // source granule
  const size_t sOff = (size_t)srow * ROWB + sg * 16;  // bytes

  // fragment-read lane geometry
  const int fr = lane & 15;   // M/N index within 16
  const int q = lane >> 4;    // quad -> k chunk of 32B
  const int swz = fr & 7;     // row&7 of the frag row

  const int raRow = (wm * 64 + fr) * 128;
  const int rbRow = (wn * 64 + fr) * 128;
  const int off0 = (q ^ swz) * 16;        // slot holding granule 2q
  const int off1 = ((q + 4) ^ swz) * 16;  // slot holding granule 2q+1

  // ---- A chunks kk=1,2,3 -> registers (frag-layout-identical gather) -------
  // Frag for (kk, m): row (I0 + wm*64 + m*16 + fr), bytes kk*128 + q*32.
  FragU uA[3][4];  // [kk-1][m], 96 VGPR
  {
    const unsigned char* aBase =
        fQ + (size_t)(I0 + wm * 64 + fr) * ROWB + q * 32;
#pragma unroll
    for (int k = 0; k < 3; ++k) {
#pragma unroll
      for (int m = 0; m < 4; ++m) {
        const unsigned char* p = aBase + (size_t)(m * 16) * ROWB + (k + 1) * 128;
        uA[k][m].h[0] = *(const int4*)(p);
        uA[k][m].h[1] = *(const int4*)(p + 16);
      }
    }
  }
  // Force the vmcnt wait for uA HERE (once, pre-pipeline) so no conservative
  // vmcnt wait lands inside the K loop.
#pragma unroll
  for (int k = 0; k < 3; ++k)
#pragma unroll
    for (int m = 0; m < 4; ++m) asm volatile("" ::"v"(uA[k][m].v));

  // ---- stage A plane kk=0: wave w stages rows w*32..+31 (4 instrs) ---------
  {
    const unsigned char* gA = fQ + (size_t)(I0 + w * 32) * ROWB + sOff;
    unsigned char* lA = ldsA0 + (w * 32) * 128;
#pragma unroll
    for (int rr = 0; rr < 32; rr += 8)
      load16_to_lds(gA + (size_t)rr * ROWB, lA + rr * 128);
  }

  // ---- prologue: stage B(Jfirst, chunk 0) into buffer 0 --------------------
  int curOff = 0;  // active B buffer byte offset (0 / 16384)
  {
    const unsigned char* gB =
        fQ + (size_t)(Jfirst * 128 + w * 32) * ROWB + sOff;
    unsigned char* lB = ldsB + (w * 32) * 128;
#pragma unroll
    for (int rr = 0; rr < 32; rr += 8)
      load16_to_lds(gB + (size_t)rr * ROWB, lB + rr * 128);
  }

  float Zp[4][4];
#pragma unroll
  for (int m = 0; m < 4; ++m)
#pragma unroll
    for (int r = 0; r < 4; ++r) Zp[m][r] = 0.0f;

  f32x4 acc[4][4];

#pragma unroll 1
  for (int J = Jfirst; J < 64; J += 8) {
    const int J0 = J * 128;
#pragma unroll
    for (int m = 0; m < 4; ++m)
#pragma unroll
      for (int n = 0; n < 4; ++n) acc[m][n] = (f32x4){0.f, 0.f, 0.f, 0.f};

    // ---- kk = 0: A from ldsA0; stage B chunk 1 ----------------------------
    {
      {  // issue B(J,1) into the other buffer
        const unsigned char* gB =
            fQ + (size_t)(J0 + w * 32) * ROWB + 1 * 128 + sOff;
        unsigned char* lB = ldsB + (curOff ^ 16384) + (w * 32) * 128;
#pragma unroll
        for (int rr = 0; rr < 32; rr += 8)
          load16_to_lds(gB + (size_t)rr * ROWB, lB + rr * 128);
      }
      VM_WAIT(4);  // A0 + B(J,0) retired; B(J,1) stays in flight
      bar_nodrain();

      const unsigned char* rbBase = ldsB + curOff + rbRow;
      i32x8 av[4];
#pragma unroll
      for (int m = 0; m < 4; ++m) {
        const unsigned char* ra = ldsA0 + raRow + m * 16 * 128;
        FragU u;
        u.h[0] = *(const int4*)(ra + off0);
        u.h[1] = *(const int4*)(ra + off1);
        av[m] = u.v;
      }
      __builtin_amdgcn_s_setprio(1);
#pragma unroll
      for (int n = 0; n < 4; ++n) {
        const unsigned char* rb = rbBase + n * 16 * 128;
        FragU ub;
        ub.h[0] = *(const int4*)(rb + off0);
        ub.h[1] = *(const int4*)(rb + off1);
#pragma unroll
        for (int m = 0; m < 4; ++m)
          acc[m][n] = __builtin_amdgcn_mfma_scale_f32_16x16x128_f8f6f4(
              av[m], ub.v, acc[m][n], 0, 0, 0, 127, 0, 127);
      }
      __builtin_amdgcn_s_setprio(0);
      bar_nodrain();  // all waves done reading buf[cur] before its reuse
      curOff ^= 16384;
    }

    // ---- kk = 1,2: A from registers; stage B chunk kk+1 --------------------
#pragma unroll
    for (int k = 0; k < 2; ++k) {
      {  // issue B(J,k+2)
        const unsigned char* gB =
            fQ + (size_t)(J0 + w * 32) * ROWB + (k + 2) * 128 + sOff;
        unsigned char* lB = ldsB + (curOff ^ 16384) + (w * 32) * 128;
#pragma unroll
        for (int rr = 0; rr < 32; rr += 8)
          load16_to_lds(gB + (size_t)rr * ROWB, lB + rr * 128);
      }
      VM_WAIT(4);  // own previous stage retired; the 4 just issued in flight
      bar_nodrain();

      const unsigned char* rbBase = ldsB + curOff + rbRow;
      __builtin_amdgcn_s_setprio(1);
#pragma unroll
      for (int n = 0; n < 4; ++n) {
        const unsigned char* rb = rbBase + n * 16 * 128;
        FragU ub;
        ub.h[0] = *(const int4*)(rb + off0);
        ub.h[1] = *(const int4*)(rb + off1);
#pragma unroll
        for (int m = 0; m < 4; ++m)
          acc[m][n] = __builtin_amdgcn_mfma_scale_f32_16x16x128_f8f6f4(
              uA[k][m].v, ub.v, acc[m][n], 0, 0, 0, 127, 0, 127);
      }
      __builtin_amdgcn_s_setprio(0);
      bar_nodrain();
      curOff ^= 16384;
    }

    // ---- kk = 3: A from registers; prefetch next J's chunk 0 ---------------
    const bool hasNext = (J + 8) < 64;
    if (hasNext) {
      const unsigned char* gB =
          fQ + (size_t)((J + 8) * 128 + w * 32) * ROWB + sOff;
      unsigned char* lB = ldsB + (curOff ^ 16384) + (w * 32) * 128;
#pragma unroll
      for (int rr = 0; rr < 32; rr += 8)
        load16_to_lds(gB + (size_t)rr * ROWB, lB + rr * 128);
      VM_WAIT(4);
    } else {
      VM_WAIT(0);  // nothing issued beyond our own last stage: full drain
    }
    bar_nodrain();
    {
      const unsigned char* rbBase = ldsB + curOff + rbRow;
      __builtin_amdgcn_s_setprio(1);
#pragma unroll
      for (int n = 0; n < 4; ++n) {
        const unsigned char* rb = rbBase + n * 16 * 128;
        FragU ub;
        ub.h[0] = *(const int4*)(rb + off0);
        ub.h[1] = *(const int4*)(rb + off1);
#pragma unroll
        for (int m = 0; m < 4; ++m)
          acc[m][n] = __builtin_amdgcn_mfma_scale_f32_16x16x128_f8f6f4(
              uA[2][m].v, ub.v, acc[m][n], 0, 0, 0, 127, 0, 127);
      }
      __builtin_amdgcn_s_setprio(0);
    }
    curOff ^= 16384;
    // Buffer-reuse barrier deferred to loop bottom — epilogue is
    // register/global-only, so waves drift while the prefetched next-J
    // chunk 0 is in flight.

    // T01: sim[0,c], sim[1,c] from rows 0,1 (band I==0 only)
    if (I == 0 && wm == 0) {
      if (q == 0) {
#pragma unroll
        for (int n = 0; n < 4; ++n) {
          const int col = J0 + wn * 64 + n * 16 + fr;
          T01[col * 2 + 0] = acc[0][n][0] * INVT;
          T01[col * 2 + 1] = acc[0][n][1] * INVT;
        }
      }
    }

    // D: diagonal dots, from the diagonal tile only
    if (J == I) {
#pragma unroll
      for (int m = 0; m < 4; ++m)
#pragma unroll
        for (int n = 0; n < 4; ++n) {
          const int col = J0 + wn * 64 + n * 16 + fr;
#pragma unroll
          for (int r = 0; r < 4; ++r) {
            const int row = I0 + wm * 64 + m * 16 + q * 4 + r;
            if (row == col) D[row] = acc[m][n][r];
          }
        }
    }

    // Z: row partials always; column sums for off-diag tiles (transpose
    // contribution to Z[J-band]).
    const bool offd = (J != I);
#pragma unroll
    for (int n = 0; n < 4; ++n) {
      float cs = 0.0f;
#pragma unroll
      for (int m = 0; m < 4; ++m)
#pragma unroll
        for (int r = 0; r < 4; ++r) {
          const float e = FAST_EXP2((acc[m][n][r] - 1.0f) * SCALE_LOG2);
          Zp[m][r] += e;
          cs += e;
        }
      if (offd) {
        cs += __shfl_xor(cs, 16);
        cs += __shfl_xor(cs, 32);
        if (q == 0) atomicAdd(&Z[J0 + wn * 64 + n * 16 + fr], cs);
      }
    }

    bar_nodrain();  // buf[cur] (just read at kk=3) may be restaged next iter
  }

  // row sums: reduce Zp across the 16 col-lanes, then atomicAdd
#pragma unroll
  for (int m = 0; m < 4; ++m)
#pragma unroll
    for (int r = 0; r < 4; ++r) {
      float v = Zp[m][r];
      v += __shfl_xor(v, 1);
      v += __shfl_xor(v, 2);
      v += __shfl_xor(v, 4);
      v += __shfl_xor(v, 8);
      if (fr == 0) atomicAdd(&Z[I0 + wm * 64 + m * 16 + q * 4 + r], v);
    }
}

// ---- K3: labels + exact-diagonal fixup + loss reduction (8 blocks) ----------
// 8 blocks x 1024 threads, 1 row each; block partial -> device atomicAdd;
// last block (ticket) writes the final scaled loss.
__global__ __launch_bounds__(1024)
void finalize_kernel(const float* __restrict__ Z,
                     const float* __restrict__ T01,
                     const float* __restrict__ D,
                     const int* __restrict__ ids,
                     const int* __restrict__ anchor,
                     float* __restrict__ S,
                     int* __restrict__ ticket,
                     float* __restrict__ out) {
  __shared__ float red[16];
  const int t = threadIdx.x;
  const int row = blockIdx.x * 1024 + t;
  const int anchor_id = ids[anchor[0]];
  const int sameLast = (ids[B_N - 1] == anchor_id);
  const int samePrev = (ids[B_N - 2] == anchor_id);
  const float z = Z[row];
  const float d = D[row];
  const float t0 = T01[row * 2 + 0];
  const float t1 = T01[row * 2 + 1];
  const int id = ids[row];

  const int same_i = (id == anchor_id);
  const int lab = (row < B_N - 1) ? (same_i & sameLast) : (sameLast & samePrev);
  const float tt = lab ? t1 : t0;
  // replace quantized diag contribution with the exact value exp(0)=1
  const float Zc = z - FAST_EXP2((d - 1.0f) * SCALE_LOG2) + 1.0f;
  float sum = tt - (INVT + logf(Zc));

#pragma unroll
  for (int off = 1; off < 64; off <<= 1) sum += __shfl_xor(sum, off);
  if ((t & 63) == 0) red[t >> 6] = sum;
  __syncthreads();
  if (t < 64) {
    float v = (t < 16) ? red[t] : 0.0f;
#pragma unroll
    for (int off = 1; off < 16; off <<= 1) v += __shfl_xor(v, off);
    if (t == 0) {
      atomicAdd(S, v);
      __threadfence();
      const int old = atomicAdd(ticket, 1);
      if (old == 7) {
        const float tot = atomicAdd(S, 0.0f);  // device-scope coherent read
        out[0] = -tot / (float)B_N;
      }
    }
  }
}

// ---------------------------------------------------------------------------
extern "C" void kernel_launch(void* const* d_in, const int* in_sizes, int n_in,
                              void* d_out, int out_size, void* d_ws, size_t ws_size,
                              hipStream_t stream) {
  const float* x = (const float*)d_in[0];
  const int* ids = (const int*)d_in[1];
  const int* anchor = (const int*)d_in[2];
  float* out = (float*)d_out;

  unsigned char* fQ = (unsigned char*)d_ws;                    // 4 MB fp8
  float* Z = (float*)((char*)d_ws + (size_t)B_N * ROWB);       // 32 KB
  float* T01 = Z + B_N;                                        // 64 KB
  float* D = T01 + 2 * B_N;                                    // 32 KB
  float* S = D + B_N;                                          // 4 B
  int* ticket = (int*)(S + 1);                                 // 4 B

  norm_kernel<<<B_N / 4, 256, 0, stream>>>(x, fQ, Z, S, ticket);
  sim_kernel<<<dim3(32, 16), 256, 0, stream>>>(fQ, Z, T01, D);
  finalize_kernel<<<8, 1024, 0, stream>>>(Z, T01, D, ids, anchor, S, ticket, out);
}